// Round 7
// baseline (116.623 us; speedup 1.0000x reference)
//
#include <hip/hip_runtime.h>
#include <hip/hip_bf16.h>

// SplineLoss: reference evaluates a not-a-knot cubic spline at INTEGER sample
// times t=0,10,...,8190 with knots at integers 0..8191 -> local parameter is
// exactly 0 for every sample, so the spline solve vanishes and the result is
// exactly:  mean_{b<1024, j<820} (true[b,10j] - pred[b,10j])^2
//
// Stride 40B < 64B line -> every line of both 32MB inputs is needed; minimum
// traffic 64MB, kernel roofline ~10.2us at 6.3TB/s. Within float4 group g
// (t=4g), samples land at .x when g%5==0 and .z when g%5==2 (256 = 1 mod 5).
//
// Session ledger:
//  R3: agent-scope RELEASE/ACQ_REL per block -> +100us (each release writes
//      back the non-coherent per-XCD L2: buffer_wbl2 x2048). Never again.
//      RELAXED agent atomics (plain atomicAdd) emit no fence -> cheap.
//  R3: VGPR=12 loop = ~2 loads in flight -> latency-bound ~1TB/s.
//  R4: 8 preloads/thread, 2048 blocks -> best so far (91.3).
//  R5: 16 preloads/thread -> no gain (94.4): not MLP-limited anymore.
//  R6: __builtin_nontemporal_load needs a NATIVE vector type, not
//      HIP_vector_type<float,4> -> use ext_vector_type(4) alias.
//  R7 (this): single dispatch. Block sum -> ONE relaxed agent-scope f32
//      atomicAdd into d_out (pre-scaled). Removes final kernel + graph-node
//      gap (~5-8us). Nontemporal loads for the read-once streams.

#define B_ROWS   1024
#define N_COLS   8192
#define N_SAMP   820
#define BLOCK    256
#define SPLIT    2                         // blocks per row
#define GRID     (B_ROWS * SPLIT)
#define GROUPS_PER_BLOCK ((N_COLS / 4) / SPLIT)   // 1024 float4 groups
#define GPT      (GROUPS_PER_BLOCK / BLOCK)       // 4 groups/thread/array

typedef float v4f __attribute__((ext_vector_type(4)));  // native vec: nt-load ok

__global__ __launch_bounds__(BLOCK)
void spline_loss_onepass(const float* __restrict__ tf,
                         const float* __restrict__ pf,
                         float* __restrict__ out) {
    const int b    = blockIdx.x >> 1;
    const int half = blockIdx.x & 1;
    const int tid  = threadIdx.x;
    const v4f* t4 = (const v4f*)(tf + (size_t)b * N_COLS);
    const v4f* p4 = (const v4f*)(pf + (size_t)b * N_COLS);

    const int g0 = half * GROUPS_PER_BLOCK + tid;

    // ---- 8 independent nontemporal global_load_dwordx4, all pre-issued ----
    v4f a[GPT], c[GPT];
    #pragma unroll
    for (int k = 0; k < GPT; ++k)
        a[k] = __builtin_nontemporal_load(&t4[g0 + BLOCK * k]);
    #pragma unroll
    for (int k = 0; k < GPT; ++k)
        c[k] = __builtin_nontemporal_load(&p4[g0 + BLOCK * k]);

    // ---- predicated squared-diff accumulate ----
    float acc = 0.0f;
    int r = g0 % 5;                        // residue advances +1 per 256 groups
    #pragma unroll
    for (int k = 0; k < GPT; ++k) {
        const float d0 = a[k].x - c[k].x;
        const float d2 = a[k].z - c[k].z;
        acc += (r == 0) ? d0 * d0 : 0.0f;
        acc += (r == 2) ? d2 * d2 : 0.0f;
        r = (r == 4) ? 0 : r + 1;
    }

    // ---- wave-64 shuffle reduction, cross-wave via LDS ----
    #pragma unroll
    for (int off = 32; off > 0; off >>= 1)
        acc += __shfl_down(acc, off, 64);

    __shared__ float wsum[BLOCK / 64];
    const int lane = tid & 63;
    const int wid  = tid >> 6;
    if (lane == 0) wsum[wid] = acc;
    __syncthreads();

    if (tid == 0) {
        float s = 0.0f;
        #pragma unroll
        for (int w = 0; w < BLOCK / 64; ++w) s += wsum[w];
        // RELAXED agent-scope fp32 atomic: no fence, no L2 writeback (the R3
        // trap was release semantics, not the atomic itself). Pipelined at
        // L2, arrivals spread across block drain -> ~us-scale tail total.
        atomicAdd(out, s * (1.0f / (float)(B_ROWS * N_SAMP)));
    }
}

extern "C" void kernel_launch(void* const* d_in, const int* in_sizes, int n_in,
                              void* d_out, int out_size, void* d_ws, size_t ws_size,
                              hipStream_t stream) {
    const float* tf = (const float*)d_in[0];   // true_frames  (1024, 8192) f32
    const float* pf = (const float*)d_in[1];   // predicted_frames
    float* out = (float*)d_out;                // scalar f32

    // d_out is poisoned 0xAA before every timed launch -> zero the 4 bytes.
    (void)hipMemsetAsync(out, 0, sizeof(float), stream);

    spline_loss_onepass<<<GRID, BLOCK, 0, stream>>>(tf, pf, out);
}

// Round 8
// 91.628 us; speedup vs baseline: 1.2728x; 1.2728x over previous
//
#include <hip/hip_runtime.h>
#include <hip/hip_bf16.h>

// SplineLoss: reference evaluates a not-a-knot cubic spline at INTEGER sample
// times t=0,10,...,8190 with knots at integers 0..8191 -> local parameter is
// exactly 0 for every sample, so the spline solve vanishes and the result is
// exactly:  mean_{b<1024, j<820} (true[b,10j] - pred[b,10j])^2
//
// Stride 40B < 64B line -> every line of both 32MB inputs is needed; minimum
// traffic 64MB. Inputs are LLC-resident (harness restores them right before
// launch), so plain loads stream at LLC BW. Within float4 group g (t=4g),
// samples land at .x when g%5==0 and .z when g%5==2 (256 = 1 mod 5).
//
// Session ledger (what's proven dead):
//  R3: agent-scope RELEASE/ACQ_REL per block -> +91us (L2 writeback storm).
//  R3: rolled loop compiled to VGPR=12 -> ~2 loads in flight -> ~450GB/s.
//      Fix = preload into named regs/unrolled array before any use.
//  R1/R7: same-address f32 atomicAdd (even RELAXED) -> ~+10us serialization.
//  R7: nontemporal loads -> +15us (they bypass the LLC that holds our
//      freshly-restored inputs; nt is anti-pollution, not a speedup here).
//  R5: 16 preloads/thread -> no gain over 8 (not MLP-limited at 8).
//  Plateau R2/R4/R5 = 91-94us across very different kernel shapes ->
//      harness fixed cost ~70us + our ~20us graph. This file = R4 config,
//      the best measured (91.3us).

#define B_ROWS   1024
#define N_COLS   8192
#define N_SAMP   820
#define BLOCK    256
#define SPLIT    2                         // blocks per row
#define GRID     (B_ROWS * SPLIT)          // 2048 partials
#define GROUPS_PER_BLOCK ((N_COLS / 4) / SPLIT)   // 1024 float4 groups
#define GPT      (GROUPS_PER_BLOCK / BLOCK)       // 4 groups/thread/array

__global__ __launch_bounds__(BLOCK)
void spline_partial_kernel(const float* __restrict__ tf,
                           const float* __restrict__ pf,
                           float* __restrict__ partial) {
    const int b    = blockIdx.x >> 1;          // row
    const int half = blockIdx.x & 1;           // which half of the row
    const int tid  = threadIdx.x;
    const float4* t4 = (const float4*)(tf + (size_t)b * N_COLS);
    const float4* p4 = (const float4*)(pf + (size_t)b * N_COLS);

    const int g0 = half * GROUPS_PER_BLOCK + tid;

    // ---- all 8 loads issued before any use: 8 x global_load_dwordx4 ----
    const float4 a0 = t4[g0];
    const float4 a1 = t4[g0 + 256];
    const float4 a2 = t4[g0 + 512];
    const float4 a3 = t4[g0 + 768];
    const float4 c0 = p4[g0];
    const float4 c1 = p4[g0 + 256];
    const float4 c2 = p4[g0 + 512];
    const float4 c3 = p4[g0 + 768];

    // ---- predicated squared-diff accumulate ----
    float acc = 0.0f;
    {
        const int r = g0 % 5;                  // 256%5==1: residue +1 per step
        float d;
        d = a0.x - c0.x; acc += (r == 0) ? d * d : 0.0f;
        d = a0.z - c0.z; acc += (r == 2) ? d * d : 0.0f;
        const int r1 = (r + 1 >= 5) ? r - 4 : r + 1;
        d = a1.x - c1.x; acc += (r1 == 0) ? d * d : 0.0f;
        d = a1.z - c1.z; acc += (r1 == 2) ? d * d : 0.0f;
        const int r2 = (r1 + 1 >= 5) ? r1 - 4 : r1 + 1;
        d = a2.x - c2.x; acc += (r2 == 0) ? d * d : 0.0f;
        d = a2.z - c2.z; acc += (r2 == 2) ? d * d : 0.0f;
        const int r3 = (r2 + 1 >= 5) ? r2 - 4 : r2 + 1;
        d = a3.x - c3.x; acc += (r3 == 0) ? d * d : 0.0f;
        d = a3.z - c3.z; acc += (r3 == 2) ? d * d : 0.0f;
    }

    // ---- wave-64 shuffle reduction, then cross-wave via LDS ----
    #pragma unroll
    for (int off = 32; off > 0; off >>= 1)
        acc += __shfl_down(acc, off, 64);

    __shared__ float wsum[BLOCK / 64];
    const int lane = tid & 63;
    const int wid  = tid >> 6;
    if (lane == 0) wsum[wid] = acc;
    __syncthreads();

    if (tid == 0) {
        float s = 0.0f;
        #pragma unroll
        for (int w = 0; w < BLOCK / 64; ++w) s += wsum[w];
        partial[blockIdx.x] = s;               // plain store; next dispatch sees it
    }
}

__global__ __launch_bounds__(BLOCK)
void spline_final_kernel(const float* __restrict__ partial,
                         float* __restrict__ out) {
    float acc = 0.0f;
    #pragma unroll
    for (int k = 0; k < GRID / BLOCK; ++k)     // 8 coalesced loads
        acc += partial[k * BLOCK + threadIdx.x];

    #pragma unroll
    for (int off = 32; off > 0; off >>= 1)
        acc += __shfl_down(acc, off, 64);

    __shared__ float wsum[BLOCK / 64];
    const int lane = threadIdx.x & 63;
    const int wid  = threadIdx.x >> 6;
    if (lane == 0) wsum[wid] = acc;
    __syncthreads();

    if (threadIdx.x == 0) {
        float s = 0.0f;
        #pragma unroll
        for (int w = 0; w < BLOCK / 64; ++w) s += wsum[w];
        out[0] = s * (1.0f / (float)(B_ROWS * N_SAMP));  // overwrite, no memset
    }
}

extern "C" void kernel_launch(void* const* d_in, const int* in_sizes, int n_in,
                              void* d_out, int out_size, void* d_ws, size_t ws_size,
                              hipStream_t stream) {
    const float* tf = (const float*)d_in[0];   // true_frames  (1024, 8192) f32
    const float* pf = (const float*)d_in[1];   // predicted_frames
    float* out     = (float*)d_out;            // scalar f32
    float* partial = (float*)d_ws;             // 2048 floats of scratch

    spline_partial_kernel<<<GRID, BLOCK, 0, stream>>>(tf, pf, partial);
    spline_final_kernel<<<1, BLOCK, 0, stream>>>(partial, out);
}